// Round 1
// baseline (1089.468 us; speedup 1.0000x reference)
//
#include <hip/hip_runtime.h>

// Encoder: per-atom top-T nearest grid points -> sum_t rbf[33] (x) (sh[9]*n*w)
// Plan: K1 select (2-pass float-bit radix hist on d2, per-atom threshold)
//       K2 compact (index lists per atom in ws)
//       K3 accumulate (bf16 MFMA 16x16x32, per-wave LDS staging, atomicAdd out)

typedef float f32x4 __attribute__((ext_vector_type(4)));
typedef int   i32x4 __attribute__((ext_vector_type(4)));

#define SLICES 16

__device__ __forceinline__ unsigned d2bits_of(float px, float py, float pz,
                                              const float* __restrict__ g, int i) {
  // MUST be bit-identical between select and compact kernels.
  float dx = px - g[3*i+0];
  float dy = py - g[3*i+1];
  float dz = pz - g[3*i+2];
  float d2 = __fmaf_rn(dx, dx, __fmaf_rn(dy, dy, __fmul_rn(dz, dz)));
  return __float_as_uint(d2);
}

__device__ __forceinline__ unsigned short tobf(float v) {
  // round-half-up f32 -> bf16
  return (unsigned short)((__float_as_uint(v) + 0x8000u) >> 16);
}

__device__ __forceinline__ void mfma_acc(f32x4& d, i32x4 a, i32x4 b) {
  asm("v_mfma_f32_16x16x32_bf16 %0, %1, %2, %0" : "+v"(d) : "v"(a), "v"(b));
}

// wave-0 finds bin where cumulative count crosses rank R; writes bin + prefix.
__device__ __forceinline__ void scan_find(const unsigned* hist, int nbins,
                                          unsigned R, unsigned* o_bin, unsigned* o_pre) {
  if (threadIdx.x < 64) {
    int lane = threadIdx.x;
    int per  = nbins >> 6;
    int base = lane * per;
    unsigned ssum = 0;
    for (int k = 0; k < per; ++k) ssum += hist[base + k];
    unsigned p = ssum;
    #pragma unroll
    for (int d = 1; d < 64; d <<= 1) {
      unsigned t = __shfl_up(p, d);
      if (lane >= d) p += t;
    }
    unsigned excl = p - ssum;                 // exclusive prefix across lanes
    if (excl < R && R <= excl + ssum) {       // unique crossing lane
      unsigned cum = excl;
      for (int k = 0; k < per; ++k) {
        unsigned h = hist[base + k];
        if (cum + h >= R) { *o_bin = (unsigned)(base + k); *o_pre = cum; break; }
        cum += h;
      }
    }
  }
}

// ---------------- K1: per-atom rank-T threshold on d2 bits ----------------
__global__ __launch_bounds__(1024) void enc_select(
    const float* __restrict__ nuc, const float* __restrict__ grid,
    int N, unsigned T, unsigned* __restrict__ thr_out) {
  __shared__ unsigned hist[8192];
  __shared__ unsigned s_bin, s_pre;
  int a = blockIdx.x;
  float px = nuc[3*a+0], py = nuc[3*a+1], pz = nuc[3*a+2];

  // pass 1: bins = bits >> 18 (sign=0 so max bin < 8192)
  for (int t = threadIdx.x; t < 8192; t += 1024) hist[t] = 0;
  __syncthreads();
  for (int i = threadIdx.x; i < N; i += 1024) {
    unsigned b = d2bits_of(px, py, pz, grid, i) >> 18;
    atomicAdd(&hist[b], 1u);
  }
  __syncthreads();
  scan_find(hist, 8192, T, &s_bin, &s_pre);
  __syncthreads();
  unsigned b1 = s_bin;
  unsigned R2 = T - s_pre;
  __syncthreads();

  // pass 2: refine bits[17:5] within bin b1
  for (int t = threadIdx.x; t < 8192; t += 1024) hist[t] = 0;
  __syncthreads();
  for (int i = threadIdx.x; i < N; i += 1024) {
    unsigned bits = d2bits_of(px, py, pz, grid, i);
    if ((bits >> 18) == b1) atomicAdd(&hist[(bits >> 5) & 0x1FFFu], 1u);
  }
  __syncthreads();
  scan_find(hist, 8192, R2, &s_bin, &s_pre);
  __syncthreads();
  if (threadIdx.x == 0) thr_out[a] = (b1 << 13) | s_bin;   // = thr_bits >> 5
}

// ---------------- K2: compact selected indices per atom ----------------
__global__ __launch_bounds__(256) void enc_compact(
    const float* __restrict__ nuc, const float* __restrict__ grid, int N,
    const unsigned* __restrict__ thr, unsigned* __restrict__ cnt,
    unsigned* __restrict__ lists, int cap) {
  int a = blockIdx.x / SLICES, s = blockIdx.x % SLICES;
  float px = nuc[3*a+0], py = nuc[3*a+1], pz = nuc[3*a+2];
  unsigned pref = thr[a];
  int per = (N + SLICES - 1) / SLICES;
  int lo = s * per, hi = min(N, lo + per);
  int lane = threadIdx.x & 63;
  for (int i = lo + threadIdx.x; i < hi; i += 256) {
    unsigned bits = d2bits_of(px, py, pz, grid, i);
    bool sel = (bits >> 5) <= pref;
    unsigned long long m = __ballot(sel);
    if (m) {
      int leader = __ffsll(m) - 1;
      unsigned base = 0;
      if (lane == leader) base = atomicAdd(&cnt[a], (unsigned)__popcll(m));
      base = __shfl(base, leader);
      if (sel) {
        unsigned pos = base + (unsigned)__popcll(m & ((1ull << lane) - 1ull));
        if (pos < (unsigned)cap) lists[(size_t)a * cap + pos] = (unsigned)i;
      }
    }
  }
}

// ---------------- K3: MFMA accumulation ----------------
// Per wave: 64 points/iter staged as bf16 into private LDS:
//   A (rbf^T): rows r=0..47 (33 used), 72-short stride; cols = point lane
//   B (v):     rows h=0..15 (9 used)
// 2 k-groups x 3 row-blocks of v_mfma_f32_16x16x32_bf16.
__global__ __launch_bounds__(256, 4) void enc_accum(
    const float* __restrict__ nuc, const float* __restrict__ grid,
    const float* __restrict__ wv, const float* __restrict__ nv,
    const unsigned* __restrict__ cnt, const unsigned* __restrict__ lists,
    int cap, float* __restrict__ out) {
  __shared__ __align__(16) unsigned short lds[4][4608];  // per-wave 3456 A + 1152 B
  int a = blockIdx.x / SLICES, s = blockIdx.x % SLICES;
  int tid = threadIdx.x, lane = tid & 63, w = tid >> 6;
  unsigned short* SB = &lds[w][0];

  { // zero this wave's region once (covers A pad rows 33..47, B rows 9..15)
    i32x4 z = {0, 0, 0, 0};
    i32x4* zp = (i32x4*)SB;
    #pragma unroll
    for (int t = 0; t < 9; ++t) zp[lane + t * 64] = z;
  }

  float px = nuc[3*a+0], py = nuc[3*a+1], pz = nuc[3*a+2];
  int total = min((int)cnt[a], cap);
  int per = (total + SLICES - 1) / SLICES;
  int lo = s * per, hi = min(total, lo + per);
  const unsigned* lst = lists + (size_t)a * cap;

  f32x4 acc0 = {0,0,0,0}, acc1 = {0,0,0,0}, acc2 = {0,0,0,0};
  int m = lane & 15, q = lane >> 4;
  const float SQRT2 = 1.41421356237309515f;
  const float PIF   = 3.14159265358979323846f;
  const float S3    = 1.73205080756887729f;

  for (int jb = lo + w * 64; jb < hi; jb += 256) {
    int j = jb + lane;
    bool valid = j < hi;
    unsigned gi = valid ? lst[j] : 0u;
    float gx = grid[3*gi+0], gy = grid[3*gi+1], gz = grid[3*gi+2];
    float dx = px - gx, dy = py - gy, dz = pz - gz;
    float d2 = __fmaf_rn(dx, dx, __fmaf_rn(dy, dy, dz * dz));
    float rn = sqrtf(d2) * 0.2f;            // normalized distance
    bool live = valid && (rn < 1.0f);       // envelope zero beyond cutoff
    if (live) {
      float x2 = rn * rn;
      float x6 = x2 * x2 * x2;
      float e  = __fmaf_rn(x6, __fmaf_rn(-21.f, x2, __fmaf_rn(48.f, rn, -28.f)), 1.f);
      float f  = SQRT2 * e;
      float nw = nv[gi] * wv[gi];
      float inv = 0.2f / (rn + 1e-15f);
      float X = dx * inv, Y = dy * inv, Z = dz * inv;
      float r2 = __fmaf_rn(X, X, __fmaf_rn(Y, Y, Z * Z));
      // B rows: v[h] = nw * sh[h]
      SB[3456 + 0*72 + lane] = tobf(nw);
      SB[3456 + 1*72 + lane] = tobf(nw * Y);
      SB[3456 + 2*72 + lane] = tobf(nw * Z);
      SB[3456 + 3*72 + lane] = tobf(nw * X);
      SB[3456 + 4*72 + lane] = tobf(nw * S3 * X * Y);
      SB[3456 + 5*72 + lane] = tobf(nw * S3 * Y * Z);
      SB[3456 + 6*72 + lane] = tobf(nw * 0.5f * __fmaf_rn(3.f, Z * Z, -r2));
      SB[3456 + 7*72 + lane] = tobf(nw * S3 * X * Z);
      SB[3456 + 8*72 + lane] = tobf(nw * 0.5f * S3 * (X * X - Y * Y));
      // A rows: rbf[r] = sqrt2*e*[0.1, sin(k pi r), cos(k pi r)]
      float s1, c1;
      sincosf(PIF * rn, &s1, &c1);
      SB[0 * 72 + lane]  = tobf(0.1f * f);
      float sk = s1, ck = c1;
      SB[1 * 72 + lane]  = tobf(f * sk);
      SB[17 * 72 + lane] = tobf(f * ck);
      #pragma unroll
      for (int k = 2; k <= 16; ++k) {
        float sn = __fmaf_rn(sk, c1, ck * s1);
        float cn = __fmaf_rn(ck, c1, -(sk * s1));
        sk = sn; ck = cn;
        SB[k * 72 + lane]        = tobf(f * sk);
        SB[(16 + k) * 72 + lane] = tobf(f * ck);
      }
    } else {
      // zero B column -> this point contributes nothing (A may be stale)
      #pragma unroll
      for (int h = 0; h < 9; ++h) SB[3456 + h * 72 + lane] = 0;
    }
    // MFMA: A[m=r][k=p], B[k=p][n=h]; lane m=l&15, k=8*(l>>4)+j (+32 per k-group)
    #pragma unroll
    for (int g = 0; g < 2; ++g) {
      int cb = 8 * q + 32 * g;
      i32x4 bf = *(const i32x4*)&SB[3456 + m * 72 + cb];
      i32x4 a0 = *(const i32x4*)&SB[(0  + m) * 72 + cb];
      mfma_acc(acc0, a0, bf);
      i32x4 a1 = *(const i32x4*)&SB[(16 + m) * 72 + cb];
      mfma_acc(acc1, a1, bf);
      i32x4 a2 = *(const i32x4*)&SB[(32 + m) * 72 + cb];
      mfma_acc(acc2, a2, bf);
    }
  }
  // MFMA -> VALU read hazard guard
  asm volatile("s_nop 7\n\ts_nop 7" : "+v"(acc0), "+v"(acc1), "+v"(acc2));
  float* op = out + (size_t)a * 297;
  if (m < 9) {
    #pragma unroll
    for (int t = 0; t < 4; ++t) {
      int row = 4 * q + t;                 // C/D: col=lane&15, row=(lane>>4)*4+t
      atomicAdd(&op[(row +  0) * 9 + m], acc0[t]);
      atomicAdd(&op[(row + 16) * 9 + m], acc1[t]);
      if (row + 32 < 33) atomicAdd(&op[(row + 32) * 9 + m], acc2[t]);
    }
  }
}

extern "C" void kernel_launch(void* const* d_in, const int* in_sizes, int n_in,
                              void* d_out, int out_size, void* d_ws, size_t ws_size,
                              hipStream_t stream) {
  const float* nuc  = (const float*)d_in[0];
  // d_in[1] = atom_mask (unused by reference math)
  const float* grid = (const float*)d_in[2];
  const float* wts  = (const float*)d_in[3];
  const float* nn   = (const float*)d_in[4];
  int A = in_sizes[0] / 3;
  int N = in_sizes[2] / 3;
  long long t8 = (8LL * (long long)N) / (long long)A;
  int T = (int)(t8 < (long long)N ? t8 : (long long)N);
  int CAP = T + 1024;
  { // degrade capacity if workspace is unexpectedly small
    long long avail = (long long)(ws_size / 4) - 2LL * A;
    if (avail > 0 && (long long)CAP * A > avail) CAP = (int)(avail / A);
  }

  unsigned* ws    = (unsigned*)d_ws;
  unsigned* thr   = ws;            // [A]
  unsigned* cnt   = ws + A;        // [A]
  unsigned* lists = ws + 2 * A;    // [A][CAP]
  float*    out   = (float*)d_out;

  hipMemsetAsync(d_out, 0, (size_t)out_size * sizeof(float), stream);
  hipMemsetAsync((void*)cnt, 0, (size_t)A * sizeof(unsigned), stream);

  enc_select <<<A,          1024, 0, stream>>>(nuc, grid, N, (unsigned)T, thr);
  enc_compact<<<A * SLICES,  256, 0, stream>>>(nuc, grid, N, thr, cnt, lists, CAP);
  enc_accum  <<<A * SLICES,  256, 0, stream>>>(nuc, grid, wts, nn, cnt, lists, CAP, out);
}

// Round 2
// 138.266 us; speedup vs baseline: 7.8795x; 7.8795x over previous
//
#include <hip/hip_runtime.h>

// Encoder: per-atom top-T nearest grid points -> sum_t rbf[33] (x) (sh[9]*n*w)
// K1 select (2-pass float-bit radix hist on d2, per-atom threshold)
// K2 compact (per-(atom,slice) segments, LDS counter -- no global atomic contention)
// K3 accumulate (bf16 MFMA 16x16x32, per-wave LDS staging, atomicAdd out)

typedef float f32x4 __attribute__((ext_vector_type(4)));
typedef int   i32x4 __attribute__((ext_vector_type(4)));

#define SLICES 16

__device__ __forceinline__ unsigned d2bits_of(float px, float py, float pz,
                                              const float* __restrict__ g, int i) {
  // MUST be bit-identical between select and compact kernels.
  float dx = px - g[3*i+0];
  float dy = py - g[3*i+1];
  float dz = pz - g[3*i+2];
  float d2 = __fmaf_rn(dx, dx, __fmaf_rn(dy, dy, __fmul_rn(dz, dz)));
  return __float_as_uint(d2);
}

__device__ __forceinline__ unsigned short tobf(float v) {
  // round-half-up f32 -> bf16
  return (unsigned short)((__float_as_uint(v) + 0x8000u) >> 16);
}

__device__ __forceinline__ void mfma_acc(f32x4& d, i32x4 a, i32x4 b) {
  asm("v_mfma_f32_16x16x32_bf16 %0, %1, %2, %0" : "+v"(d) : "v"(a), "v"(b));
}

// wave-0 finds bin where cumulative count crosses rank R; writes bin + prefix.
__device__ __forceinline__ void scan_find(const unsigned* hist, int nbins,
                                          unsigned R, unsigned* o_bin, unsigned* o_pre) {
  if (threadIdx.x < 64) {
    int lane = threadIdx.x;
    int per  = nbins >> 6;
    int base = lane * per;
    unsigned ssum = 0;
    for (int k = 0; k < per; ++k) ssum += hist[base + k];
    unsigned p = ssum;
    #pragma unroll
    for (int d = 1; d < 64; d <<= 1) {
      unsigned t = __shfl_up(p, d);
      if (lane >= d) p += t;
    }
    unsigned excl = p - ssum;                 // exclusive prefix across lanes
    if (excl < R && R <= excl + ssum) {       // unique crossing lane
      unsigned cum = excl;
      for (int k = 0; k < per; ++k) {
        unsigned h = hist[base + k];
        if (cum + h >= R) { *o_bin = (unsigned)(base + k); *o_pre = cum; break; }
        cum += h;
      }
    }
  }
}

// ---------------- K1: per-atom rank-T threshold on d2 bits ----------------
__global__ __launch_bounds__(1024) void enc_select(
    const float* __restrict__ nuc, const float* __restrict__ grid,
    int N, unsigned T, unsigned* __restrict__ thr_out) {
  __shared__ unsigned hist[8192];
  __shared__ unsigned s_bin, s_pre;
  int a = blockIdx.x;
  float px = nuc[3*a+0], py = nuc[3*a+1], pz = nuc[3*a+2];

  // pass 1: bins = bits >> 18 (sign=0 so max bin < 8192)
  for (int t = threadIdx.x; t < 8192; t += 1024) hist[t] = 0;
  __syncthreads();
  for (int i = threadIdx.x; i < N; i += 1024) {
    unsigned b = d2bits_of(px, py, pz, grid, i) >> 18;
    atomicAdd(&hist[b], 1u);
  }
  __syncthreads();
  scan_find(hist, 8192, T, &s_bin, &s_pre);
  __syncthreads();
  unsigned b1 = s_bin;
  unsigned R2 = T - s_pre;
  __syncthreads();

  // pass 2: refine bits[17:5] within bin b1
  for (int t = threadIdx.x; t < 8192; t += 1024) hist[t] = 0;
  __syncthreads();
  for (int i = threadIdx.x; i < N; i += 1024) {
    unsigned bits = d2bits_of(px, py, pz, grid, i);
    if ((bits >> 18) == b1) atomicAdd(&hist[(bits >> 5) & 0x1FFFu], 1u);
  }
  __syncthreads();
  scan_find(hist, 8192, R2, &s_bin, &s_pre);
  __syncthreads();
  if (threadIdx.x == 0) thr_out[a] = (b1 << 13) | s_bin;   // = thr_bits >> 5
}

// ---------------- K2: compact selected indices, per-(atom,slice) segment ----------------
__global__ __launch_bounds__(256) void enc_compact(
    const float* __restrict__ nuc, const float* __restrict__ grid, int N,
    const unsigned* __restrict__ thr, unsigned* __restrict__ cnt,
    unsigned* __restrict__ lists, int scap) {
  __shared__ unsigned s_cnt;
  if (threadIdx.x == 0) s_cnt = 0;
  __syncthreads();

  int a = blockIdx.x / SLICES, s = blockIdx.x % SLICES;
  float px = nuc[3*a+0], py = nuc[3*a+1], pz = nuc[3*a+2];
  unsigned pref = thr[a];
  int per = (N + SLICES - 1) / SLICES;
  int lo = s * per, hi = min(N, lo + per);
  int lane = threadIdx.x & 63;
  unsigned* seg = lists + (size_t)(a * SLICES + s) * scap;

  for (int i = lo + threadIdx.x; i < hi; i += 256) {
    unsigned bits = d2bits_of(px, py, pz, grid, i);
    bool sel = (bits >> 5) <= pref;
    unsigned long long m = __ballot(sel);
    if (m) {
      int leader = __ffsll(m) - 1;
      unsigned base = 0;
      if (lane == leader) base = atomicAdd(&s_cnt, (unsigned)__popcll(m));
      base = __shfl(base, leader);
      if (sel) {
        unsigned pos = base + (unsigned)__popcll(m & ((1ull << lane) - 1ull));
        if (pos < (unsigned)scap) seg[pos] = (unsigned)i;
      }
    }
  }
  __syncthreads();
  if (threadIdx.x == 0) cnt[a * SLICES + s] = s_cnt;
}

// ---------------- K3: MFMA accumulation over one (atom,slice) segment ----------------
// Per wave: 64 points/iter staged as bf16 into private LDS:
//   A (rbf^T): rows r=0..47 (33 used), 72-short stride; cols = point lane
//   B (v):     rows h=0..15 (9 used)
// 2 k-groups x 3 row-blocks of v_mfma_f32_16x16x32_bf16.
__global__ __launch_bounds__(256, 4) void enc_accum(
    const float* __restrict__ nuc, const float* __restrict__ grid,
    const float* __restrict__ wv, const float* __restrict__ nv,
    const unsigned* __restrict__ cnt, const unsigned* __restrict__ lists,
    int scap, float* __restrict__ out) {
  __shared__ __align__(16) unsigned short lds[4][4608];  // per-wave 3456 A + 1152 B
  int a = blockIdx.x / SLICES, s = blockIdx.x % SLICES;
  int tid = threadIdx.x, lane = tid & 63, w = tid >> 6;
  unsigned short* SB = &lds[w][0];

  { // zero this wave's region once (covers A pad rows 33..47, B rows 9..15)
    i32x4 z = {0, 0, 0, 0};
    i32x4* zp = (i32x4*)SB;
    #pragma unroll
    for (int t = 0; t < 9; ++t) zp[lane + t * 64] = z;
  }

  float px = nuc[3*a+0], py = nuc[3*a+1], pz = nuc[3*a+2];
  int seg_id = a * SLICES + s;
  int total = min((int)cnt[seg_id], scap);
  const unsigned* lst = lists + (size_t)seg_id * scap;

  f32x4 acc0 = {0,0,0,0}, acc1 = {0,0,0,0}, acc2 = {0,0,0,0};
  int m = lane & 15, q = lane >> 4;
  const float SQRT2 = 1.41421356237309515f;
  const float PIF   = 3.14159265358979323846f;
  const float S3    = 1.73205080756887729f;

  for (int jb = w * 64; jb < total; jb += 256) {
    int j = jb + lane;
    bool valid = j < total;
    unsigned gi = valid ? lst[j] : 0u;
    float gx = grid[3*gi+0], gy = grid[3*gi+1], gz = grid[3*gi+2];
    float dx = px - gx, dy = py - gy, dz = pz - gz;
    float d2 = __fmaf_rn(dx, dx, __fmaf_rn(dy, dy, dz * dz));
    float rn = sqrtf(d2) * 0.2f;            // normalized distance
    bool live = valid && (rn < 1.0f);       // envelope zero beyond cutoff
    if (live) {
      float x2 = rn * rn;
      float x6 = x2 * x2 * x2;
      float e  = __fmaf_rn(x6, __fmaf_rn(-21.f, x2, __fmaf_rn(48.f, rn, -28.f)), 1.f);
      float f  = SQRT2 * e;
      float nw = nv[gi] * wv[gi];
      float inv = 0.2f / (rn + 1e-15f);
      float X = dx * inv, Y = dy * inv, Z = dz * inv;
      float r2 = __fmaf_rn(X, X, __fmaf_rn(Y, Y, Z * Z));
      // B rows: v[h] = nw * sh[h]
      SB[3456 + 0*72 + lane] = tobf(nw);
      SB[3456 + 1*72 + lane] = tobf(nw * Y);
      SB[3456 + 2*72 + lane] = tobf(nw * Z);
      SB[3456 + 3*72 + lane] = tobf(nw * X);
      SB[3456 + 4*72 + lane] = tobf(nw * S3 * X * Y);
      SB[3456 + 5*72 + lane] = tobf(nw * S3 * Y * Z);
      SB[3456 + 6*72 + lane] = tobf(nw * 0.5f * __fmaf_rn(3.f, Z * Z, -r2));
      SB[3456 + 7*72 + lane] = tobf(nw * S3 * X * Z);
      SB[3456 + 8*72 + lane] = tobf(nw * 0.5f * S3 * (X * X - Y * Y));
      // A rows: rbf[r] = sqrt2*e*[0.1, sin(k pi r), cos(k pi r)]
      float s1, c1;
      sincosf(PIF * rn, &s1, &c1);
      SB[0 * 72 + lane]  = tobf(0.1f * f);
      float sk = s1, ck = c1;
      SB[1 * 72 + lane]  = tobf(f * sk);
      SB[17 * 72 + lane] = tobf(f * ck);
      #pragma unroll
      for (int k = 2; k <= 16; ++k) {
        float sn = __fmaf_rn(sk, c1, ck * s1);
        float cn = __fmaf_rn(ck, c1, -(sk * s1));
        sk = sn; ck = cn;
        SB[k * 72 + lane]        = tobf(f * sk);
        SB[(16 + k) * 72 + lane] = tobf(f * ck);
      }
    } else {
      // zero B column -> this point contributes nothing (A may be stale)
      #pragma unroll
      for (int h = 0; h < 9; ++h) SB[3456 + h * 72 + lane] = 0;
    }
    // MFMA: A[m=r][k=p], B[k=p][n=h]; lane m=l&15, k=8*(l>>4)+j (+32 per k-group)
    #pragma unroll
    for (int g = 0; g < 2; ++g) {
      int cb = 8 * q + 32 * g;
      i32x4 bf = *(const i32x4*)&SB[3456 + m * 72 + cb];
      i32x4 a0 = *(const i32x4*)&SB[(0  + m) * 72 + cb];
      mfma_acc(acc0, a0, bf);
      i32x4 a1 = *(const i32x4*)&SB[(16 + m) * 72 + cb];
      mfma_acc(acc1, a1, bf);
      i32x4 a2 = *(const i32x4*)&SB[(32 + m) * 72 + cb];
      mfma_acc(acc2, a2, bf);
    }
  }
  // MFMA -> VALU read hazard guard
  asm volatile("s_nop 7\n\ts_nop 7" : "+v"(acc0), "+v"(acc1), "+v"(acc2));
  float* op = out + (size_t)a * 297;
  if (m < 9) {
    #pragma unroll
    for (int t = 0; t < 4; ++t) {
      int row = 4 * q + t;                 // C/D: col=lane&15, row=(lane>>4)*4+t
      atomicAdd(&op[(row +  0) * 9 + m], acc0[t]);
      atomicAdd(&op[(row + 16) * 9 + m], acc1[t]);
      if (row + 32 < 33) atomicAdd(&op[(row + 32) * 9 + m], acc2[t]);
    }
  }
}

extern "C" void kernel_launch(void* const* d_in, const int* in_sizes, int n_in,
                              void* d_out, int out_size, void* d_ws, size_t ws_size,
                              hipStream_t stream) {
  const float* nuc  = (const float*)d_in[0];
  // d_in[1] = atom_mask (unused by reference math)
  const float* grid = (const float*)d_in[2];
  const float* wts  = (const float*)d_in[3];
  const float* nn   = (const float*)d_in[4];
  int A = in_sizes[0] / 3;
  int N = in_sizes[2] / 3;
  long long t8 = (8LL * (long long)N) / (long long)A;
  int T = (int)(t8 < (long long)N ? t8 : (long long)N);

  // per-(atom,slice) segment capacity: mean T/SLICES, +512 (>13 sigma) slack
  int SCAP = T / SLICES + 512;
  { // degrade capacity if workspace is unexpectedly small
    long long avail = (long long)(ws_size / 4) - (long long)A * SLICES;
    long long need  = (long long)SCAP * A * SLICES;
    if (avail > 0 && need > avail) SCAP = (int)(avail / ((long long)A * SLICES));
  }

  unsigned* ws    = (unsigned*)d_ws;
  unsigned* cnt   = ws;                    // [A*SLICES]
  unsigned* lists = ws + A * SLICES;       // [A*SLICES][SCAP]
  unsigned* thr   = lists + (size_t)A * SLICES * SCAP;  // [A] (reuse tail? no: keep separate)
  // place thr safely: it is A u32s; lists sized by SCAP clamp leaves room only
  // if we reserved it -- instead carve thr from the front:
  // layout: [cnt A*SLICES][thr A][lists ...]
  thr   = ws + A * SLICES;
  lists = thr + A;
  float* out = (float*)d_out;

  hipMemsetAsync(d_out, 0, (size_t)out_size * sizeof(float), stream);
  hipMemsetAsync((void*)cnt, 0, (size_t)A * SLICES * sizeof(unsigned), stream);

  enc_select <<<A,          1024, 0, stream>>>(nuc, grid, N, (unsigned)T, thr);
  enc_compact<<<A * SLICES,  256, 0, stream>>>(nuc, grid, N, thr, cnt, lists, SCAP);
  enc_accum  <<<A * SLICES,  256, 0, stream>>>(nuc, grid, wts, nn, cnt, lists, SCAP, out);
}

// Round 3
// 119.971 us; speedup vs baseline: 9.0811x; 1.1525x over previous
//
#include <hip/hip_runtime.h>

// Encoder: per-atom top-T nearest grid points -> sum_t rbf[33] (x) (sh[9]*n*w)
// K1a hist1 (A*SLICES blocks, LDS hist of d2-bits>>18, merge to global)
// K1b scan1 (per-atom crossing bin b1 + residual rank R2; re-zeroes hist)
// K2a hist2 (refine bits[17:5] within bin b1)
// K2b scan2 (final 32-ULP threshold)
// K3  compact (per-(atom,slice) segments, LDS counter)
// K4  accum (bf16 MFMA 16x16x32, per-wave LDS staging, atomicAdd out)

typedef float f32x4 __attribute__((ext_vector_type(4)));
typedef int   i32x4 __attribute__((ext_vector_type(4)));

#define SLICES 16
#define HBINS  8192

__device__ __forceinline__ unsigned d2bits_of(float px, float py, float pz,
                                              const float* __restrict__ g, int i) {
  // MUST be bit-identical across hist/compact kernels.
  float dx = px - g[3*i+0];
  float dy = py - g[3*i+1];
  float dz = pz - g[3*i+2];
  float d2 = __fmaf_rn(dx, dx, __fmaf_rn(dy, dy, __fmul_rn(dz, dz)));
  return __float_as_uint(d2);
}

__device__ __forceinline__ unsigned short tobf(float v) {
  // round-half-up f32 -> bf16
  return (unsigned short)((__float_as_uint(v) + 0x8000u) >> 16);
}

__device__ __forceinline__ void mfma_acc(f32x4& d, i32x4 a, i32x4 b) {
  asm("v_mfma_f32_16x16x32_bf16 %0, %1, %2, %0" : "+v"(d) : "v"(a), "v"(b));
}

// first 64 lanes: find bin where cumulative count crosses rank R; write bin+prefix.
__device__ __forceinline__ void scan_find(const unsigned* hist, int nbins,
                                          unsigned R, unsigned* o_bin, unsigned* o_pre) {
  if (threadIdx.x < 64) {
    int lane = threadIdx.x;
    int per  = nbins >> 6;
    int base = lane * per;
    unsigned ssum = 0;
    for (int k = 0; k < per; ++k) ssum += hist[base + k];
    unsigned p = ssum;
    #pragma unroll
    for (int d = 1; d < 64; d <<= 1) {
      unsigned t = __shfl_up(p, d);
      if (lane >= d) p += t;
    }
    unsigned excl = p - ssum;                 // exclusive prefix across lanes
    if (excl < R && R <= excl + ssum) {       // unique crossing lane
      unsigned cum = excl;
      for (int k = 0; k < per; ++k) {
        unsigned h = hist[base + k];
        if (cum + h >= R) { *o_bin = (unsigned)(base + k); *o_pre = cum; break; }
        cum += h;
      }
    }
  }
}

// ---------------- K1a: partial histograms of bits>>18, merged globally ----------------
__global__ __launch_bounds__(256) void enc_hist1(
    const float* __restrict__ nuc, const float* __restrict__ grid, int N,
    unsigned* __restrict__ ghist) {
  __shared__ unsigned lh[HBINS];
  int a = blockIdx.x / SLICES, s = blockIdx.x % SLICES;
  for (int t = threadIdx.x; t < HBINS; t += 256) lh[t] = 0;
  __syncthreads();
  float px = nuc[3*a+0], py = nuc[3*a+1], pz = nuc[3*a+2];
  int per = (N + SLICES - 1) / SLICES;
  int lo = s * per, hi = min(N, lo + per);
  for (int i = lo + threadIdx.x; i < hi; i += 256) {
    unsigned b = d2bits_of(px, py, pz, grid, i) >> 18;   // d2>=0 finite -> b<8192
    atomicAdd(&lh[b], 1u);
  }
  __syncthreads();
  unsigned* gh = ghist + (size_t)a * HBINS;
  for (int t = threadIdx.x; t < HBINS; t += 256) {
    unsigned v = lh[t];
    if (v) atomicAdd(&gh[t], v);
  }
}

// ---------------- K1b: per-atom scan -> b1, R2; re-zero hist for pass 2 ----------------
__global__ __launch_bounds__(64) void enc_scan1(
    unsigned* __restrict__ ghist, unsigned T,
    unsigned* __restrict__ b1r, unsigned* __restrict__ r2r) {
  __shared__ unsigned s_bin, s_pre;
  int a = blockIdx.x;
  unsigned* gh = ghist + (size_t)a * HBINS;
  scan_find(gh, HBINS, T, &s_bin, &s_pre);
  __syncthreads();
  if (threadIdx.x == 0) { b1r[a] = s_bin; r2r[a] = T - s_pre; }
  __syncthreads();
  for (int t = threadIdx.x; t < HBINS; t += 64) gh[t] = 0;
}

// ---------------- K2a: refine bits[17:5] within bin b1 ----------------
__global__ __launch_bounds__(256) void enc_hist2(
    const float* __restrict__ nuc, const float* __restrict__ grid, int N,
    const unsigned* __restrict__ b1r, unsigned* __restrict__ ghist) {
  __shared__ unsigned lh[HBINS];
  int a = blockIdx.x / SLICES, s = blockIdx.x % SLICES;
  for (int t = threadIdx.x; t < HBINS; t += 256) lh[t] = 0;
  __syncthreads();
  float px = nuc[3*a+0], py = nuc[3*a+1], pz = nuc[3*a+2];
  unsigned b1 = b1r[a];
  int per = (N + SLICES - 1) / SLICES;
  int lo = s * per, hi = min(N, lo + per);
  for (int i = lo + threadIdx.x; i < hi; i += 256) {
    unsigned bits = d2bits_of(px, py, pz, grid, i);
    if ((bits >> 18) == b1) atomicAdd(&lh[(bits >> 5) & (HBINS - 1)], 1u);
  }
  __syncthreads();
  unsigned* gh = ghist + (size_t)a * HBINS;
  for (int t = threadIdx.x; t < HBINS; t += 256) {
    unsigned v = lh[t];
    if (v) atomicAdd(&gh[t], v);
  }
}

// ---------------- K2b: final threshold (= thr_bits >> 5) ----------------
__global__ __launch_bounds__(64) void enc_scan2(
    const unsigned* __restrict__ ghist, const unsigned* __restrict__ b1r,
    const unsigned* __restrict__ r2r, unsigned* __restrict__ thr) {
  __shared__ unsigned s_bin, s_pre;
  int a = blockIdx.x;
  scan_find(ghist + (size_t)a * HBINS, HBINS, r2r[a], &s_bin, &s_pre);
  __syncthreads();
  if (threadIdx.x == 0) thr[a] = (b1r[a] << 13) | s_bin;
}

// ---------------- K3: compact selected indices, per-(atom,slice) segment ----------------
__global__ __launch_bounds__(256) void enc_compact(
    const float* __restrict__ nuc, const float* __restrict__ grid, int N,
    const unsigned* __restrict__ thr, unsigned* __restrict__ cnt,
    unsigned* __restrict__ lists, int scap) {
  __shared__ unsigned s_cnt;
  if (threadIdx.x == 0) s_cnt = 0;
  __syncthreads();

  int a = blockIdx.x / SLICES, s = blockIdx.x % SLICES;
  float px = nuc[3*a+0], py = nuc[3*a+1], pz = nuc[3*a+2];
  unsigned pref = thr[a];
  int per = (N + SLICES - 1) / SLICES;
  int lo = s * per, hi = min(N, lo + per);
  int lane = threadIdx.x & 63;
  unsigned* seg = lists + (size_t)(a * SLICES + s) * scap;

  for (int i = lo + threadIdx.x; i < hi; i += 256) {
    unsigned bits = d2bits_of(px, py, pz, grid, i);
    bool sel = (bits >> 5) <= pref;
    unsigned long long m = __ballot(sel);
    if (m) {
      int leader = __ffsll(m) - 1;
      unsigned base = 0;
      if (lane == leader) base = atomicAdd(&s_cnt, (unsigned)__popcll(m));
      base = __shfl(base, leader);
      if (sel) {
        unsigned pos = base + (unsigned)__popcll(m & ((1ull << lane) - 1ull));
        if (pos < (unsigned)scap) seg[pos] = (unsigned)i;
      }
    }
  }
  __syncthreads();
  if (threadIdx.x == 0) cnt[a * SLICES + s] = s_cnt;
}

// ---------------- K4: MFMA accumulation over one (atom,slice) segment ----------------
__global__ __launch_bounds__(256, 4) void enc_accum(
    const float* __restrict__ nuc, const float* __restrict__ grid,
    const float* __restrict__ wv, const float* __restrict__ nv,
    const unsigned* __restrict__ cnt, const unsigned* __restrict__ lists,
    int scap, float* __restrict__ out) {
  __shared__ __align__(16) unsigned short lds[4][4608];  // per-wave 3456 A + 1152 B
  int a = blockIdx.x / SLICES, s = blockIdx.x % SLICES;
  int tid = threadIdx.x, lane = tid & 63, w = tid >> 6;
  unsigned short* SB = &lds[w][0];

  { // zero this wave's region once (covers A pad rows 33..47, B rows 9..15)
    i32x4 z = {0, 0, 0, 0};
    i32x4* zp = (i32x4*)SB;
    #pragma unroll
    for (int t = 0; t < 9; ++t) zp[lane + t * 64] = z;
  }

  float px = nuc[3*a+0], py = nuc[3*a+1], pz = nuc[3*a+2];
  int seg_id = a * SLICES + s;
  int total = min((int)cnt[seg_id], scap);
  const unsigned* lst = lists + (size_t)seg_id * scap;

  f32x4 acc0 = {0,0,0,0}, acc1 = {0,0,0,0}, acc2 = {0,0,0,0};
  int m = lane & 15, q = lane >> 4;
  const float SQRT2 = 1.41421356237309515f;
  const float PIF   = 3.14159265358979323846f;
  const float S3    = 1.73205080756887729f;

  for (int jb = w * 64; jb < total; jb += 256) {
    int j = jb + lane;
    bool valid = j < total;
    unsigned gi = valid ? lst[j] : 0u;
    float gx = grid[3*gi+0], gy = grid[3*gi+1], gz = grid[3*gi+2];
    float dx = px - gx, dy = py - gy, dz = pz - gz;
    float d2 = __fmaf_rn(dx, dx, __fmaf_rn(dy, dy, dz * dz));
    float rn = sqrtf(d2) * 0.2f;            // normalized distance
    bool live = valid && (rn < 1.0f);       // envelope zero beyond cutoff
    if (live) {
      float x2 = rn * rn;
      float x6 = x2 * x2 * x2;
      float e  = __fmaf_rn(x6, __fmaf_rn(-21.f, x2, __fmaf_rn(48.f, rn, -28.f)), 1.f);
      float f  = SQRT2 * e;
      float nw = nv[gi] * wv[gi];
      float inv = 0.2f / (rn + 1e-15f);
      float X = dx * inv, Y = dy * inv, Z = dz * inv;
      float r2 = __fmaf_rn(X, X, __fmaf_rn(Y, Y, Z * Z));
      // B rows: v[h] = nw * sh[h]
      SB[3456 + 0*72 + lane] = tobf(nw);
      SB[3456 + 1*72 + lane] = tobf(nw * Y);
      SB[3456 + 2*72 + lane] = tobf(nw * Z);
      SB[3456 + 3*72 + lane] = tobf(nw * X);
      SB[3456 + 4*72 + lane] = tobf(nw * S3 * X * Y);
      SB[3456 + 5*72 + lane] = tobf(nw * S3 * Y * Z);
      SB[3456 + 6*72 + lane] = tobf(nw * 0.5f * __fmaf_rn(3.f, Z * Z, -r2));
      SB[3456 + 7*72 + lane] = tobf(nw * S3 * X * Z);
      SB[3456 + 8*72 + lane] = tobf(nw * 0.5f * S3 * (X * X - Y * Y));
      // A rows: rbf[r] = sqrt2*e*[0.1, sin(k pi r), cos(k pi r)]
      float s1, c1;
      sincosf(PIF * rn, &s1, &c1);
      SB[0 * 72 + lane]  = tobf(0.1f * f);
      float sk = s1, ck = c1;
      SB[1 * 72 + lane]  = tobf(f * sk);
      SB[17 * 72 + lane] = tobf(f * ck);
      #pragma unroll
      for (int k = 2; k <= 16; ++k) {
        float sn = __fmaf_rn(sk, c1, ck * s1);
        float cn = __fmaf_rn(ck, c1, -(sk * s1));
        sk = sn; ck = cn;
        SB[k * 72 + lane]        = tobf(f * sk);
        SB[(16 + k) * 72 + lane] = tobf(f * ck);
      }
    } else {
      // zero B column -> this point contributes nothing (A may be stale)
      #pragma unroll
      for (int h = 0; h < 9; ++h) SB[3456 + h * 72 + lane] = 0;
    }
    // MFMA: A[m=r][k=p], B[k=p][n=h]; lane m=l&15, k=8*(l>>4)+j (+32 per k-group)
    #pragma unroll
    for (int g = 0; g < 2; ++g) {
      int cb = 8 * q + 32 * g;
      i32x4 bf = *(const i32x4*)&SB[3456 + m * 72 + cb];
      i32x4 a0 = *(const i32x4*)&SB[(0  + m) * 72 + cb];
      mfma_acc(acc0, a0, bf);
      i32x4 a1 = *(const i32x4*)&SB[(16 + m) * 72 + cb];
      mfma_acc(acc1, a1, bf);
      i32x4 a2 = *(const i32x4*)&SB[(32 + m) * 72 + cb];
      mfma_acc(acc2, a2, bf);
    }
  }
  // MFMA -> VALU read hazard guard
  asm volatile("s_nop 7\n\ts_nop 7" : "+v"(acc0), "+v"(acc1), "+v"(acc2));
  float* op = out + (size_t)a * 297;
  if (m < 9) {
    #pragma unroll
    for (int t = 0; t < 4; ++t) {
      int row = 4 * q + t;                 // C/D: col=lane&15, row=(lane>>4)*4+t
      atomicAdd(&op[(row +  0) * 9 + m], acc0[t]);
      atomicAdd(&op[(row + 16) * 9 + m], acc1[t]);
      if (row + 32 < 33) atomicAdd(&op[(row + 32) * 9 + m], acc2[t]);
    }
  }
}

extern "C" void kernel_launch(void* const* d_in, const int* in_sizes, int n_in,
                              void* d_out, int out_size, void* d_ws, size_t ws_size,
                              hipStream_t stream) {
  const float* nuc  = (const float*)d_in[0];
  // d_in[1] = atom_mask (unused by reference math)
  const float* grid = (const float*)d_in[2];
  const float* wts  = (const float*)d_in[3];
  const float* nn   = (const float*)d_in[4];
  int A = in_sizes[0] / 3;
  int N = in_sizes[2] / 3;
  long long t8 = (8LL * (long long)N) / (long long)A;
  int T = (int)(t8 < (long long)N ? t8 : (long long)N);

  // ws layout: [cnt A*SLICES][thr A][b1 A][r2 A][ghist A*HBINS][lists ...]
  unsigned* ws    = (unsigned*)d_ws;
  unsigned* cnt   = ws;
  unsigned* thr   = cnt + A * SLICES;
  unsigned* b1r   = thr + A;
  unsigned* r2r   = b1r + A;
  unsigned* ghist = r2r + A;
  unsigned* lists = ghist + (size_t)A * HBINS;

  // per-(atom,slice) segment capacity: mean T/SLICES, +512 (>13 sigma) slack
  int SCAP = T / SLICES + 512;
  {
    long long head  = (long long)(lists - ws);
    long long avail = (long long)(ws_size / 4) - head;
    long long need  = (long long)SCAP * A * SLICES;
    if (avail > 0 && need > avail) SCAP = (int)(avail / ((long long)A * SLICES));
  }
  float* out = (float*)d_out;

  hipMemsetAsync(d_out, 0, (size_t)out_size * sizeof(float), stream);
  hipMemsetAsync((void*)cnt, 0, (size_t)A * SLICES * sizeof(unsigned), stream);
  hipMemsetAsync((void*)ghist, 0, (size_t)A * HBINS * sizeof(unsigned), stream);

  enc_hist1  <<<A * SLICES, 256, 0, stream>>>(nuc, grid, N, ghist);
  enc_scan1  <<<A,           64, 0, stream>>>(ghist, (unsigned)T, b1r, r2r);
  enc_hist2  <<<A * SLICES, 256, 0, stream>>>(nuc, grid, N, b1r, ghist);
  enc_scan2  <<<A,           64, 0, stream>>>(ghist, b1r, r2r, thr);
  enc_compact<<<A * SLICES, 256, 0, stream>>>(nuc, grid, N, thr, cnt, lists, SCAP);
  enc_accum  <<<A * SLICES, 256, 0, stream>>>(nuc, grid, wts, nn, cnt, lists, SCAP, out);
}

// Round 4
// 115.633 us; speedup vs baseline: 9.4218x; 1.0375x over previous
//
#include <hip/hip_runtime.h>

// Encoder: per-atom top-T nearest grid points -> sum_t rbf[33] (x) (sh[9]*n*w)
// K0  zero (ghist + out; replaces hipMemsetAsync -- blit fills cost ~40us each in graph)
// K1a hist1 (A*SLICES blocks, LDS hist of d2-bits>>18, merge to global)
// K1b scan1 (per-atom crossing bin b1 + residual rank R2; re-zeroes hist)
// K2a hist2 (refine bits[17:5] within bin b1)
// K2b scan2 (final 32-ULP threshold)
// K3  compact (per-(atom,slice) segments, LDS counter)
// K4  accum (bf16 MFMA 16x16x32, per-wave LDS staging, atomicAdd out)

typedef float f32x4 __attribute__((ext_vector_type(4)));
typedef int   i32x4 __attribute__((ext_vector_type(4)));

#define SLICES 16
#define HBINS  8192

__device__ __forceinline__ unsigned d2bits_of(float px, float py, float pz,
                                              const float* __restrict__ g, int i) {
  // MUST be bit-identical across hist/compact kernels.
  float dx = px - g[3*i+0];
  float dy = py - g[3*i+1];
  float dz = pz - g[3*i+2];
  float d2 = __fmaf_rn(dx, dx, __fmaf_rn(dy, dy, __fmul_rn(dz, dz)));
  return __float_as_uint(d2);
}

__device__ __forceinline__ unsigned short tobf(float v) {
  // round-half-up f32 -> bf16
  return (unsigned short)((__float_as_uint(v) + 0x8000u) >> 16);
}

__device__ __forceinline__ void mfma_acc(f32x4& d, i32x4 a, i32x4 b) {
  asm("v_mfma_f32_16x16x32_bf16 %0, %1, %2, %0" : "+v"(d) : "v"(a), "v"(b));
}

// first 64 lanes: find bin where cumulative count crosses rank R; write bin+prefix.
__device__ __forceinline__ void scan_find(const unsigned* hist, int nbins,
                                          unsigned R, unsigned* o_bin, unsigned* o_pre) {
  if (threadIdx.x < 64) {
    int lane = threadIdx.x;
    int per  = nbins >> 6;
    int base = lane * per;
    unsigned ssum = 0;
    for (int k = 0; k < per; ++k) ssum += hist[base + k];
    unsigned p = ssum;
    #pragma unroll
    for (int d = 1; d < 64; d <<= 1) {
      unsigned t = __shfl_up(p, d);
      if (lane >= d) p += t;
    }
    unsigned excl = p - ssum;                 // exclusive prefix across lanes
    if (excl < R && R <= excl + ssum) {       // unique crossing lane
      unsigned cum = excl;
      for (int k = 0; k < per; ++k) {
        unsigned h = hist[base + k];
        if (cum + h >= R) { *o_bin = (unsigned)(base + k); *o_pre = cum; break; }
        cum += h;
      }
    }
  }
}

// ---------------- K0: zero ghist + out (one cheap compute dispatch) ----------------
__global__ __launch_bounds__(256) void enc_zero(
    i32x4* __restrict__ gh, int nh4, i32x4* __restrict__ ob, int no4) {
  int i = blockIdx.x * 256 + threadIdx.x;
  int stride = gridDim.x * 256;
  i32x4 z = {0, 0, 0, 0};
  for (int t = i; t < nh4; t += stride) gh[t] = z;
  for (int t = i; t < no4; t += stride) ob[t] = z;
}

// ---------------- K1a: partial histograms of bits>>18, merged globally ----------------
__global__ __launch_bounds__(256) void enc_hist1(
    const float* __restrict__ nuc, const float* __restrict__ grid, int N,
    unsigned* __restrict__ ghist) {
  __shared__ unsigned lh[HBINS];
  int a = blockIdx.x / SLICES, s = blockIdx.x % SLICES;
  for (int t = threadIdx.x; t < HBINS; t += 256) lh[t] = 0;
  __syncthreads();
  float px = nuc[3*a+0], py = nuc[3*a+1], pz = nuc[3*a+2];
  int per = (N + SLICES - 1) / SLICES;
  int lo = s * per, hi = min(N, lo + per);
  for (int i = lo + threadIdx.x; i < hi; i += 256) {
    unsigned b = d2bits_of(px, py, pz, grid, i) >> 18;   // d2>=0 finite -> b<8192
    atomicAdd(&lh[b], 1u);
  }
  __syncthreads();
  unsigned* gh = ghist + (size_t)a * HBINS;
  for (int t = threadIdx.x; t < HBINS; t += 256) {
    unsigned v = lh[t];
    if (v) atomicAdd(&gh[t], v);
  }
}

// ---------------- K1b: per-atom scan -> b1, R2; re-zero hist for pass 2 ----------------
__global__ __launch_bounds__(64) void enc_scan1(
    unsigned* __restrict__ ghist, unsigned T,
    unsigned* __restrict__ b1r, unsigned* __restrict__ r2r) {
  __shared__ unsigned s_bin, s_pre;
  int a = blockIdx.x;
  unsigned* gh = ghist + (size_t)a * HBINS;
  scan_find(gh, HBINS, T, &s_bin, &s_pre);
  __syncthreads();
  if (threadIdx.x == 0) { b1r[a] = s_bin; r2r[a] = T - s_pre; }
  __syncthreads();
  for (int t = threadIdx.x; t < HBINS; t += 64) gh[t] = 0;
}

// ---------------- K2a: refine bits[17:5] within bin b1 ----------------
__global__ __launch_bounds__(256) void enc_hist2(
    const float* __restrict__ nuc, const float* __restrict__ grid, int N,
    const unsigned* __restrict__ b1r, unsigned* __restrict__ ghist) {
  __shared__ unsigned lh[HBINS];
  int a = blockIdx.x / SLICES, s = blockIdx.x % SLICES;
  for (int t = threadIdx.x; t < HBINS; t += 256) lh[t] = 0;
  __syncthreads();
  float px = nuc[3*a+0], py = nuc[3*a+1], pz = nuc[3*a+2];
  unsigned b1 = b1r[a];
  int per = (N + SLICES - 1) / SLICES;
  int lo = s * per, hi = min(N, lo + per);
  for (int i = lo + threadIdx.x; i < hi; i += 256) {
    unsigned bits = d2bits_of(px, py, pz, grid, i);
    if ((bits >> 18) == b1) atomicAdd(&lh[(bits >> 5) & (HBINS - 1)], 1u);
  }
  __syncthreads();
  unsigned* gh = ghist + (size_t)a * HBINS;
  for (int t = threadIdx.x; t < HBINS; t += 256) {
    unsigned v = lh[t];
    if (v) atomicAdd(&gh[t], v);
  }
}

// ---------------- K2b: final threshold (= thr_bits >> 5) ----------------
__global__ __launch_bounds__(64) void enc_scan2(
    const unsigned* __restrict__ ghist, const unsigned* __restrict__ b1r,
    const unsigned* __restrict__ r2r, unsigned* __restrict__ thr) {
  __shared__ unsigned s_bin, s_pre;
  int a = blockIdx.x;
  scan_find(ghist + (size_t)a * HBINS, HBINS, r2r[a], &s_bin, &s_pre);
  __syncthreads();
  if (threadIdx.x == 0) thr[a] = (b1r[a] << 13) | s_bin;
}

// ---------------- K3: compact selected indices, per-(atom,slice) segment ----------------
__global__ __launch_bounds__(256) void enc_compact(
    const float* __restrict__ nuc, const float* __restrict__ grid, int N,
    const unsigned* __restrict__ thr, unsigned* __restrict__ cnt,
    unsigned* __restrict__ lists, int scap) {
  __shared__ unsigned s_cnt;
  if (threadIdx.x == 0) s_cnt = 0;
  __syncthreads();

  int a = blockIdx.x / SLICES, s = blockIdx.x % SLICES;
  float px = nuc[3*a+0], py = nuc[3*a+1], pz = nuc[3*a+2];
  unsigned pref = thr[a];
  int per = (N + SLICES - 1) / SLICES;
  int lo = s * per, hi = min(N, lo + per);
  int lane = threadIdx.x & 63;
  unsigned* seg = lists + (size_t)(a * SLICES + s) * scap;

  for (int i = lo + threadIdx.x; i < hi; i += 256) {
    unsigned bits = d2bits_of(px, py, pz, grid, i);
    bool sel = (bits >> 5) <= pref;
    unsigned long long m = __ballot(sel);
    if (m) {
      int leader = __ffsll(m) - 1;
      unsigned base = 0;
      if (lane == leader) base = atomicAdd(&s_cnt, (unsigned)__popcll(m));
      base = __shfl(base, leader);
      if (sel) {
        unsigned pos = base + (unsigned)__popcll(m & ((1ull << lane) - 1ull));
        if (pos < (unsigned)scap) seg[pos] = (unsigned)i;
      }
    }
  }
  __syncthreads();
  if (threadIdx.x == 0) cnt[a * SLICES + s] = s_cnt;   // plain store: no pre-zero needed
}

// ---------------- K4: MFMA accumulation over one (atom,slice) segment ----------------
__global__ __launch_bounds__(256, 4) void enc_accum(
    const float* __restrict__ nuc, const float* __restrict__ grid,
    const float* __restrict__ wv, const float* __restrict__ nv,
    const unsigned* __restrict__ cnt, const unsigned* __restrict__ lists,
    int scap, float* __restrict__ out) {
  __shared__ __align__(16) unsigned short lds[4][4608];  // per-wave 3456 A + 1152 B
  int a = blockIdx.x / SLICES, s = blockIdx.x % SLICES;
  int tid = threadIdx.x, lane = tid & 63, w = tid >> 6;
  unsigned short* SB = &lds[w][0];

  { // zero this wave's region once (covers A pad rows 33..47, B rows 9..15)
    i32x4 z = {0, 0, 0, 0};
    i32x4* zp = (i32x4*)SB;
    #pragma unroll
    for (int t = 0; t < 9; ++t) zp[lane + t * 64] = z;
  }

  float px = nuc[3*a+0], py = nuc[3*a+1], pz = nuc[3*a+2];
  int seg_id = a * SLICES + s;
  int total = min((int)cnt[seg_id], scap);
  const unsigned* lst = lists + (size_t)seg_id * scap;

  f32x4 acc0 = {0,0,0,0}, acc1 = {0,0,0,0}, acc2 = {0,0,0,0};
  int m = lane & 15, q = lane >> 4;
  const float SQRT2 = 1.41421356237309515f;
  const float PIF   = 3.14159265358979323846f;
  const float S3    = 1.73205080756887729f;

  for (int jb = w * 64; jb < total; jb += 256) {
    int j = jb + lane;
    bool valid = j < total;
    unsigned gi = valid ? lst[j] : 0u;
    float gx = grid[3*gi+0], gy = grid[3*gi+1], gz = grid[3*gi+2];
    float dx = px - gx, dy = py - gy, dz = pz - gz;
    float d2 = __fmaf_rn(dx, dx, __fmaf_rn(dy, dy, dz * dz));
    float rn = sqrtf(d2) * 0.2f;            // normalized distance
    bool live = valid && (rn < 1.0f);       // envelope zero beyond cutoff
    if (live) {
      float x2 = rn * rn;
      float x6 = x2 * x2 * x2;
      float e  = __fmaf_rn(x6, __fmaf_rn(-21.f, x2, __fmaf_rn(48.f, rn, -28.f)), 1.f);
      float f  = SQRT2 * e;
      float nw = nv[gi] * wv[gi];
      float inv = 0.2f / (rn + 1e-15f);
      float X = dx * inv, Y = dy * inv, Z = dz * inv;
      float r2 = __fmaf_rn(X, X, __fmaf_rn(Y, Y, Z * Z));
      // B rows: v[h] = nw * sh[h]
      SB[3456 + 0*72 + lane] = tobf(nw);
      SB[3456 + 1*72 + lane] = tobf(nw * Y);
      SB[3456 + 2*72 + lane] = tobf(nw * Z);
      SB[3456 + 3*72 + lane] = tobf(nw * X);
      SB[3456 + 4*72 + lane] = tobf(nw * S3 * X * Y);
      SB[3456 + 5*72 + lane] = tobf(nw * S3 * Y * Z);
      SB[3456 + 6*72 + lane] = tobf(nw * 0.5f * __fmaf_rn(3.f, Z * Z, -r2));
      SB[3456 + 7*72 + lane] = tobf(nw * S3 * X * Z);
      SB[3456 + 8*72 + lane] = tobf(nw * 0.5f * S3 * (X * X - Y * Y));
      // A rows: rbf[r] = sqrt2*e*[0.1, sin(k pi r), cos(k pi r)]
      float s1, c1;
      sincosf(PIF * rn, &s1, &c1);
      SB[0 * 72 + lane]  = tobf(0.1f * f);
      float sk = s1, ck = c1;
      SB[1 * 72 + lane]  = tobf(f * sk);
      SB[17 * 72 + lane] = tobf(f * ck);
      #pragma unroll
      for (int k = 2; k <= 16; ++k) {
        float sn = __fmaf_rn(sk, c1, ck * s1);
        float cn = __fmaf_rn(ck, c1, -(sk * s1));
        sk = sn; ck = cn;
        SB[k * 72 + lane]        = tobf(f * sk);
        SB[(16 + k) * 72 + lane] = tobf(f * ck);
      }
    } else {
      // zero B column -> this point contributes nothing (A may be stale)
      #pragma unroll
      for (int h = 0; h < 9; ++h) SB[3456 + h * 72 + lane] = 0;
    }
    // MFMA: A[m=r][k=p], B[k=p][n=h]; lane m=l&15, k=8*(l>>4)+j (+32 per k-group)
    #pragma unroll
    for (int g = 0; g < 2; ++g) {
      int cb = 8 * q + 32 * g;
      i32x4 bf = *(const i32x4*)&SB[3456 + m * 72 + cb];
      i32x4 a0 = *(const i32x4*)&SB[(0  + m) * 72 + cb];
      mfma_acc(acc0, a0, bf);
      i32x4 a1 = *(const i32x4*)&SB[(16 + m) * 72 + cb];
      mfma_acc(acc1, a1, bf);
      i32x4 a2 = *(const i32x4*)&SB[(32 + m) * 72 + cb];
      mfma_acc(acc2, a2, bf);
    }
  }
  // MFMA -> VALU read hazard guard
  asm volatile("s_nop 7\n\ts_nop 7" : "+v"(acc0), "+v"(acc1), "+v"(acc2));
  float* op = out + (size_t)a * 297;
  if (m < 9) {
    #pragma unroll
    for (int t = 0; t < 4; ++t) {
      int row = 4 * q + t;                 // C/D: col=lane&15, row=(lane>>4)*4+t
      atomicAdd(&op[(row +  0) * 9 + m], acc0[t]);
      atomicAdd(&op[(row + 16) * 9 + m], acc1[t]);
      if (row + 32 < 33) atomicAdd(&op[(row + 32) * 9 + m], acc2[t]);
    }
  }
}

extern "C" void kernel_launch(void* const* d_in, const int* in_sizes, int n_in,
                              void* d_out, int out_size, void* d_ws, size_t ws_size,
                              hipStream_t stream) {
  const float* nuc  = (const float*)d_in[0];
  // d_in[1] = atom_mask (unused by reference math)
  const float* grid = (const float*)d_in[2];
  const float* wts  = (const float*)d_in[3];
  const float* nn   = (const float*)d_in[4];
  int A = in_sizes[0] / 3;
  int N = in_sizes[2] / 3;
  long long t8 = (8LL * (long long)N) / (long long)A;
  int T = (int)(t8 < (long long)N ? t8 : (long long)N);

  // ws layout: [cnt A*SLICES][thr A][b1 A][r2 A][ghist A*HBINS][lists ...]
  unsigned* ws    = (unsigned*)d_ws;
  unsigned* cnt   = ws;
  unsigned* thr   = cnt + A * SLICES;
  unsigned* b1r   = thr + A;
  unsigned* r2r   = b1r + A;
  unsigned* ghist = r2r + A;
  unsigned* lists = ghist + (size_t)A * HBINS;

  // per-(atom,slice) segment capacity: mean T/SLICES, +512 (>13 sigma) slack
  int SCAP = T / SLICES + 512;
  {
    long long head  = (long long)(lists - ws);
    long long avail = (long long)(ws_size / 4) - head;
    long long need  = (long long)SCAP * A * SLICES;
    if (avail > 0 && need > avail) SCAP = (int)(avail / ((long long)A * SLICES));
  }
  float* out = (float*)d_out;

  int nh4 = (A * HBINS) / 4;          // ghist dwords / 4 (A*HBINS multiple of 4)
  int no4 = out_size / 4;             // out elements / 4 (A*297 = 19008, /4 ok)
  enc_zero   <<<512,        256, 0, stream>>>((i32x4*)ghist, nh4, (i32x4*)out, no4);
  enc_hist1  <<<A * SLICES, 256, 0, stream>>>(nuc, grid, N, ghist);
  enc_scan1  <<<A,           64, 0, stream>>>(ghist, (unsigned)T, b1r, r2r);
  enc_hist2  <<<A * SLICES, 256, 0, stream>>>(nuc, grid, N, b1r, ghist);
  enc_scan2  <<<A,           64, 0, stream>>>(ghist, b1r, r2r, thr);
  enc_compact<<<A * SLICES, 256, 0, stream>>>(nuc, grid, N, thr, cnt, lists, SCAP);
  enc_accum  <<<A * SLICES, 256, 0, stream>>>(nuc, grid, wts, nn, cnt, lists, SCAP, out);
}